// Round 10
// baseline (38.130 us; speedup 1.0000x reference)
//
#include <hip/hip_runtime.h>
#include <hip/hip_bf16.h>
#include <stdint.h>

typedef short short8 __attribute__((ext_vector_type(8)));
typedef float f32x4 __attribute__((ext_vector_type(4)));
typedef unsigned short ushort4_t __attribute__((ext_vector_type(4)));
typedef unsigned short ushort8_t __attribute__((ext_vector_type(8)));

#define S_LEN 2048
#define NQKV 1536
#define DMODEL 512

__device__ inline unsigned short f2bf(float f) {
  unsigned int u = __float_as_uint(f);
  unsigned int r = (u + 0x7FFFu + ((u >> 16) & 1u)) >> 16;
  return (unsigned short)r;
}

// async global->LDS, 16B per lane. LDS dest must be linear in lane order.
__device__ __forceinline__ void gll16(const unsigned short* g, unsigned short* l) {
  __builtin_amdgcn_global_load_lds(
      (const __attribute__((address_space(1))) unsigned int*)g,
      (__attribute__((address_space(3))) unsigned int*)l, 16, 0, 0);
}

// ---------------- fused prep: x->bf16, weight transposes, pad zeroing --------
__global__ __launch_bounds__(256) void k_prep(const float* __restrict__ x,
                                              unsigned short* __restrict__ xb,
                                              const float* __restrict__ w1,
                                              unsigned short* __restrict__ o1,
                                              const float* __restrict__ w2,
                                              unsigned short* __restrict__ o2,
                                              unsigned short* __restrict__ Kp,
                                              unsigned short* __restrict__ Vp) {
  __shared__ float T[32][33];
  int bid = blockIdx.x;
  int t = threadIdx.x;
  if (bid < 1024) {
    int i = (bid * 256 + t) * 8;
    float4 a = *(const float4*)(x + i);
    float4 b = *(const float4*)(x + i + 4);
    ushort8_t o;
    o[0] = f2bf(a.x); o[1] = f2bf(a.y); o[2] = f2bf(a.z); o[3] = f2bf(a.w);
    o[4] = f2bf(b.x); o[5] = f2bf(b.y); o[6] = f2bf(b.z); o[7] = f2bf(b.w);
    *(ushort8_t*)(xb + i) = o;
    return;
  }
  if (bid >= 2048) {  // pad zeroing: Kp rows [0,32)+[2080,2112); Vp cols same
    int p = bid - 2048;
    ushort8_t z = {};
    if (p < 16) {
      unsigned short* dst = Kp + (size_t)p * 2112 * 64;
#pragma unroll
      for (int i = 0; i < 2; i++) {
        int s = t + 256 * i;
        int row = s >> 3, c = s & 7;
        int r2 = row < 32 ? row : row - 32 + 2080;
        *(ushort8_t*)&dst[r2 * 64 + c * 8] = z;
      }
    } else {
      unsigned short* dst = Vp + (size_t)(p - 16) * 64 * 2112;
#pragma unroll
      for (int i = 0; i < 2; i++) {
        int s = t + 256 * i;
        int d = s >> 3, side = (s >> 2) & 1, c = s & 3;
        *(ushort8_t*)&dst[(size_t)d * 2112 + side * 2080 + c * 8] = z;
      }
    }
    return;
  }
  bid -= 1024;
  int bx = bid & 63, byy = bid >> 6;
  const float* w; unsigned short* o; int cols;
  if (bx < 48) { w = w1; o = o1; cols = 1536; }
  else         { w = w2; o = o2; cols = 512; bx -= 48; }
  int r0 = byy * 32, c0 = bx * 32;
  int tr = t / 32, tc = t % 32;
#pragma unroll
  for (int i = 0; i < 4; i++) {
    int r = tr + i * 8;
    T[r][tc] = w[(size_t)(r0 + r) * cols + c0 + tc];
  }
  __syncthreads();
#pragma unroll
  for (int i = 0; i < 4; i++) {
    int rr = tr + i * 8;
    o[(size_t)(c0 + rr) * 512 + r0 + tc] = f2bf(T[tc][rr]);
  }
}

// ---------------- gemm1: qkv projection, 2-wave blocks, 64x64 wave tiles -----
// BM=128, BN=64, BK=64, K=512. 128 threads = 2 waves; wave w owns rows w*64..+63
// and ALL 64 cols (MR=4, NR=4). A fragments read 1x (no wave duplication).
// Both-sides XOR swizzle on stage source + ds_read. Outputs de-interleaved
// Qs / Kp(+32 pos pad) / Vp(transposed), contiguous 16B stores.
__global__ __launch_bounds__(128) void k_gemm1(const unsigned short* __restrict__ A,
                                               const unsigned short* __restrict__ Bt,
                                               unsigned short* __restrict__ qs,
                                               unsigned short* __restrict__ kp,
                                               unsigned short* __restrict__ vp) {
  __shared__ __align__(16) unsigned short smem[24576];  // 48 KB
  const int ASZ = 128 * 64, BOFF = 2 * 128 * 64, BSZ = 64 * 64;
  const int t = threadIdx.x, lane = t & 63, wid = t >> 6;
  const int m0 = blockIdx.y * 128, n0 = blockIdx.x * 64;
  const int wm = wid * 64;
  const int lr = lane & 15, lg = lane >> 4;
  const unsigned short* Ab = A + (size_t)m0 * 512;
  const unsigned short* Bb = Bt + (size_t)n0 * 512;
  f32x4 acc[4][4] = {};

  auto stage = [&](int buf, int kt) {
#pragma unroll
    for (int c = 0; c < 8; c++) {      // A: 128 rows x 8 chunks / 128 thr
      int f = t + 128 * c;
      int row = f >> 3, ch = f & 7;
      gll16(Ab + (size_t)row * 512 + kt + ((ch ^ (row & 7)) << 3),
            &smem[buf * ASZ + f * 8]);
    }
#pragma unroll
    for (int c = 0; c < 4; c++) {      // B: 64 rows x 8 chunks / 128 thr
      int f = t + 128 * c;
      int row = f >> 3, ch = f & 7;
      gll16(Bb + (size_t)row * 512 + kt + ((ch ^ (row & 7)) << 3),
            &smem[BOFF + buf * BSZ + f * 8]);
    }
  };

  stage(0, 0);
  int buf = 0;
  for (int it = 0; it < 8; ++it) {
    __syncthreads();
    if (it + 1 < 8) stage(buf ^ 1, (it + 1) * 64);
    const unsigned short* Ap = &smem[buf * ASZ];
    const unsigned short* Bp = &smem[BOFF + buf * BSZ];
#pragma unroll
    for (int sl = 0; sl < 2; sl++) {
      const int cs = sl * 4 + lg;      // 16B chunk within the 64-elem k row
      short8 af[4], bfv[4];
#pragma unroll
      for (int i = 0; i < 4; i++) {
        int row = wm + i * 16 + lr;
        af[i] = *(const short8*)&Ap[row * 64 + ((cs ^ (row & 7)) << 3)];
      }
#pragma unroll
      for (int i = 0; i < 4; i++) {
        int row = i * 16 + lr;
        bfv[i] = *(const short8*)&Bp[row * 64 + ((cs ^ (row & 7)) << 3)];
      }
#pragma unroll
      for (int mi = 0; mi < 4; mi++)
#pragma unroll
        for (int ni = 0; ni < 4; ni++)
          acc[mi][ni] = __builtin_amdgcn_mfma_f32_16x16x32_bf16(af[mi], bfv[ni], acc[mi][ni], 0, 0, 0);
    }
    buf ^= 1;
  }

  // ---- swizzled bf16 bounce [128][64] ----
  __syncthreads();
#pragma unroll
  for (int mi = 0; mi < 4; mi++)
#pragma unroll
    for (int ni = 0; ni < 4; ni++)
#pragma unroll
      for (int j = 0; j < 4; j++) {
        int row = wm + mi * 16 + lg * 4 + j;
        int col = ni * 16 + lr;
        smem[row * 64 + (((col >> 3) ^ ((row >> 3) & 7)) << 3) + (col & 7)] =
            f2bf(acc[mi][ni][j]);
      }
  __syncthreads();

  const int b_ = m0 >> 11;
  const int posb = m0 & 2047;
  const int h = n0 / 192, seg = (n0 % 192) >> 6;  // 0=q, 1=k, 2=v
  if (seg < 2) {
    unsigned short* dst = (seg == 0)
        ? qs + ((size_t)(b_ * 8 + h) * 2048 + posb) * 64
        : kp + ((size_t)(b_ * 8 + h) * 2112 + 32 + posb) * 64;
#pragma unroll
    for (int i = 0; i < 8; i++) {
      int s = t + 128 * i;              // 1024 chunks: 128 rows x 8
      int row = s >> 3, ch = s & 7;
      int src = row * 64 + ((ch ^ ((row >> 3) & 7)) << 3);
      *(ushort8_t*)&dst[s * 8] = *(const ushort8_t*)&smem[src];
    }
  } else {
    unsigned short* dst = vp + (size_t)(b_ * 8 + h) * 64 * 2112;
#pragma unroll
    for (int i = 0; i < 8; i++) {
      int s = t + 128 * i;              // dl 0..63, pc 0..15
      int dl = s >> 4, pc = s & 15;
      ushort8_t v;
#pragma unroll
      for (int j = 0; j < 8; j++) {
        int row = pc * 8 + j;
        v[j] = smem[row * 64 + ((((dl >> 3) ^ (pc & 7)) << 3)) + (dl & 7)];
      }
      *(ushort8_t*)&dst[(size_t)dl * 2112 + 32 + posb + pc * 8] = v;
    }
  }
}

// ---------------- gemm2: C[M][N] = A*Bt^T, f32 out + bias (unchanged) --------
template <int BM, int BN>
__global__ __launch_bounds__(256) void k_gemm(const unsigned short* __restrict__ A,
                                              const unsigned short* __restrict__ Bt,
                                              float* __restrict__ Cout,
                                              const float* __restrict__ bias,
                                              int M, int N, int K) {
  constexpr int MR = BM / 32, NR = BN / 32;
  constexpr int CA = BM / 32, CB = BN / 32;
  constexpr int STAGE_SH = 2 * (BM + BN) * 64;
  constexpr int BOUNCE_SH = BM * BN * 2;
  constexpr int SMEM_SH = STAGE_SH > BOUNCE_SH ? STAGE_SH : BOUNCE_SH;
  __shared__ __align__(16) unsigned short smem[SMEM_SH];
  const int ASZ = BM * 64, BOFF = 2 * BM * 64, BSZ = BN * 64;

  const int t = threadIdx.x, lane = t & 63, wid = t >> 6;
  const int m0 = blockIdx.y * BM, n0 = blockIdx.x * BN;
  const int wm = (wid >> 1) * (BM / 2), wn = (wid & 1) * (BN / 2);
  const int lr = lane & 15, lg = lane >> 4;
  const unsigned short* Ab = A + (size_t)m0 * K;
  const unsigned short* Bb = Bt + (size_t)n0 * K;
  f32x4 acc[MR][NR] = {};

  const int NT = K / 64;
  auto stage = [&](int buf, int kt) {
#pragma unroll
    for (int c = 0; c < CA; c++) {
      int f = t + 256 * c;
      int row = f >> 3, ch = f & 7;
      gll16(Ab + (size_t)row * K + kt + ((ch ^ (row & 7)) << 3),
            &smem[buf * ASZ + f * 8]);
    }
#pragma unroll
    for (int c = 0; c < CB; c++) {
      int f = t + 256 * c;
      int row = f >> 3, ch = f & 7;
      gll16(Bb + (size_t)row * K + kt + ((ch ^ (row & 7)) << 3),
            &smem[BOFF + buf * BSZ + f * 8]);
    }
  };

  stage(0, 0);
  int buf = 0;
  for (int it = 0; it < NT; ++it) {
    __syncthreads();
    if (it + 1 < NT) stage(buf ^ 1, (it + 1) * 64);
    const unsigned short* Ap = &smem[buf * ASZ];
    const unsigned short* Bp = &smem[BOFF + buf * BSZ];
#pragma unroll
    for (int sl = 0; sl < 2; sl++) {
      const int cs = sl * 4 + lg;
      short8 af[MR], bfv[NR];
#pragma unroll
      for (int i = 0; i < MR; i++) {
        int row = wm + i * 16 + lr;
        af[i] = *(const short8*)&Ap[row * 64 + ((cs ^ (row & 7)) << 3)];
      }
#pragma unroll
      for (int i = 0; i < NR; i++) {
        int row = wn + i * 16 + lr;
        bfv[i] = *(const short8*)&Bp[row * 64 + ((cs ^ (row & 7)) << 3)];
      }
#pragma unroll
      for (int mi = 0; mi < MR; mi++)
#pragma unroll
        for (int ni = 0; ni < NR; ni++)
          acc[mi][ni] = __builtin_amdgcn_mfma_f32_16x16x32_bf16(af[mi], bfv[ni], acc[mi][ni], 0, 0, 0);
    }
    buf ^= 1;
  }

  // ---- f32 bounce: [BM][BN] f32, coalesced float4 stores + bias ----
  __syncthreads();
  float* ft = (float*)smem;
#pragma unroll
  for (int mi = 0; mi < MR; mi++)
#pragma unroll
    for (int ni = 0; ni < NR; ni++)
#pragma unroll
      for (int j = 0; j < 4; j++)
        ft[(wm + mi * 16 + lg * 4 + j) * BN + wn + ni * 16 + lr] = acc[mi][ni][j];
  __syncthreads();
#pragma unroll
  for (int i = 0; i < BM * BN / 1024; i++) {
    int s = t + 256 * i;
    int row = s / (BN / 4), ch = s % (BN / 4);
    float4 v = *(const float4*)&ft[row * BN + ch * 4];
    float4 bv = *(const float4*)&bias[n0 + ch * 4];
    v.x += bv.x; v.y += bv.y; v.z += bv.z; v.w += bv.w;
    *(float4*)&Cout[(size_t)(m0 + row) * N + n0 + ch * 4] = v;
  }
}

// ---------------- windowed attention: LDS-staged, swizzled, branch-free ------
__global__ __launch_bounds__(256) void k_attn(const unsigned short* __restrict__ Qs,
                                              const unsigned short* __restrict__ Kp,
                                              const unsigned short* __restrict__ Vp,
                                              unsigned short* __restrict__ attnb) {
  __shared__ __align__(16) unsigned short Kt[128 * 64];  // pos-local x d, swz
  __shared__ __align__(16) unsigned short Vt[64 * 192];  // d x pos-local, swz
  __shared__ __align__(16) unsigned short Qt[64 * 64];   // q-local x d, swz
  const int t = threadIdx.x, lane = t & 63, w = t >> 6;
  const int blk = blockIdx.x;
  const int sbi = blk & 31, h = (blk >> 5) & 7, b = blk >> 8;
  const int sb = sbi * 64;
  const int bh = b * 8 + h;
  const int lr = lane & 15, lg = lane >> 4;

  {  // stage K: Kp idx sb..sb+127 (= global pos sb-32..sb+95)
    const unsigned short* src = Kp + ((size_t)bh * 2112 + sb) * 64;
#pragma unroll
    for (int i = 0; i < 4; i++) {
      int s = t + 256 * i, row = s >> 3, c = s & 7;
      gll16(src + row * 64 + (c ^ (row & 7)) * 8, &Kt[s * 8]);
    }
  }
  {  // stage V: Vp cols sb..sb+191 (= global pos sb-32..sb+159)
    const unsigned short* src = Vp + (size_t)bh * 64 * 2112 + sb;
#pragma unroll
    for (int i = 0; i < 6; i++) {
      int s = t + 256 * i, d = s / 24, c = s - d * 24;
      gll16(src + (size_t)d * 2112 + (c ^ (d & 7)) * 8, &Vt[s * 8]);
    }
  }
  {  // stage Q: rows sb..sb+63
    const unsigned short* src = Qs + ((size_t)bh * 2048 + sb) * 64;
#pragma unroll
    for (int i = 0; i < 2; i++) {
      int s = t + 256 * i, row = s >> 3, c = s & 7;
      gll16(src + row * 64 + (c ^ (row & 7)) * 8, &Qt[s * 8]);
    }
  }
  __syncthreads();

  const int sw = (lr & 7) << 3;  // u16 read-XOR (16B chunks)

  short8 qb[2];
#pragma unroll
  for (int ks = 0; ks < 2; ks++)
    qb[ks] = *(const short8*)&Qt[(w * 16 + lr) * 64 + ((ks * 32 + lg * 8) ^ sw)];

  // S^T: col = q = lr, row = pos_local(rel s0-32) = ct*16 + lg*4 + j
  f32x4 sc[5] = {};
#pragma unroll
  for (int ct = 0; ct < 5; ct++) {
#pragma unroll
    for (int ks = 0; ks < 2; ks++) {
      short8 ka = *(const short8*)&Kt[(w * 16 + ct * 16 + lr) * 64 + ((ks * 32 + lg * 8) ^ sw)];
      sc[ct] = __builtin_amdgcn_mfma_f32_16x16x32_bf16(ka, qb[ks], sc[ct], 0, 0, 0);
    }
  }

  float mx = -1e30f;
#pragma unroll
  for (int ct = 0; ct < 5; ct++)
#pragma unroll
    for (int j = 0; j < 4; j++) {
      int c2 = ct * 16 + lg * 4 + j;
      sc[ct][j] = (c2 >= lr && c2 <= lr + 64) ? sc[ct][j] * 0.125f : -1e30f;
      mx = fmaxf(mx, sc[ct][j]);
    }
  mx = fmaxf(mx, __shfl_xor(mx, 16, 64));
  mx = fmaxf(mx, __shfl_xor(mx, 32, 64));

  float pn[5][4];
  float sum = 0.0f;
#pragma unroll
  for (int ct = 0; ct < 5; ct++)
#pragma unroll
    for (int j = 0; j < 4; j++) {
      pn[ct][j] = __expf(sc[ct][j] - mx);
      sum += pn[ct][j];
    }
  sum += __shfl_xor(sum, 16, 64);
  sum += __shfl_xor(sum, 32, 64);
  float inv = 1.0f / sum;

  unsigned int w01[5], w23[5];
#pragma unroll
  for (int ct = 0; ct < 5; ct++) {
    w01[ct] = (unsigned int)f2bf(pn[ct][0] * inv) | ((unsigned int)f2bf(pn[ct][1] * inv) << 16);
    w23[ct] = (unsigned int)f2bf(pn[ct][2] * inv) | ((unsigned int)f2bf(pn[ct][3] * inv) << 16);
  }

  f32x4 oa[4] = {};
  const int h2 = lg & 1, tl = lg >> 1;
  const int sA = 32 * h2 + lr, sB = sA + 16;
#pragma unroll
  for (int ks = 0; ks < 3; ks++) {
    const int T0 = 2 * ks;
    const int T1 = (2 * ks + 1 < 5) ? (2 * ks + 1) : 4;
    unsigned int a0 = __shfl((int)w01[T0], sA, 64), a1 = __shfl((int)w23[T0], sA, 64);
    unsigned int a2 = __shfl((int)w01[T0], sB, 64), a3 = __shfl((int)w23[T0], sB, 64);
    unsigned int b0 = __shfl((int)w01[T1], sA, 64), b1 = __shfl((int)w23[T1], sA, 64);
    unsigned int b2 = __shfl((int)w01[T1], sB, 64), b3 = __shfl((int)w23[T1], sB, 64);
    union { unsigned int u[4]; short8 v; } pb;
    pb.u[0] = tl ? b0 : a0;
    pb.u[1] = tl ? b1 : a1;
    pb.u[2] = tl ? b2 : a2;
    pb.u[3] = tl ? b3 : a3;
    if (ks == 2 && tl) { pb.u[0] = 0; pb.u[1] = 0; pb.u[2] = 0; pb.u[3] = 0; }
    int pofl = w * 16 + ks * 32 + lg * 8;
#pragma unroll
    for (int nt = 0; nt < 4; nt++) {
      short8 va = *(const short8*)&Vt[(nt * 16 + lr) * 192 + (pofl ^ sw)];
      oa[nt] = __builtin_amdgcn_mfma_f32_16x16x32_bf16(va, pb.v, oa[nt], 0, 0, 0);
    }
  }

  const int s0 = sb + w * 16;
#pragma unroll
  for (int nt = 0; nt < 4; nt++) {
    ushort4_t o;
#pragma unroll
    for (int j = 0; j < 4; j++) o[j] = f2bf(oa[nt][j]);
    *(ushort4_t*)&attnb[((size_t)b * S_LEN + s0 + lr) * DMODEL + h * 64 + nt * 16 + lg * 4] = o;
  }
}

// ---------------- launch ----------------
extern "C" void kernel_launch(void* const* d_in, const int* in_sizes, int n_in,
                              void* d_out, int out_size, void* d_ws, size_t ws_size,
                              hipStream_t stream) {
  const float* x    = (const float*)d_in[0];
  const float* Wqkv = (const float*)d_in[1];
  const float* Wout = (const float*)d_in[2];
  const float* bout = (const float*)d_in[3];
  char* ws = (char*)d_ws;
  unsigned short* xb    = (unsigned short*)(ws + 0);         // 4096x512 bf16 (4 MB)
  unsigned short* wqkvt = (unsigned short*)(ws + 4194304);   // 1536x512 bf16 (1.5 MB)
  unsigned short* woutt = (unsigned short*)(ws + 5767168);   // 512x512 bf16  (0.5 MB)
  unsigned short* Qs    = (unsigned short*)(ws + 6291456);   // [16][2048][64] (4 MB)
  unsigned short* Kp    = (unsigned short*)(ws + 10485760);  // [16][2112][64] (4.125 MB)
  unsigned short* Vp    = (unsigned short*)(ws + 14811136);  // [16][64][2112] (4.125 MB + slack)
  unsigned short* attnb = (unsigned short*)(ws + 19922944);  // 4096x512 bf16 (4 MB)

  hipLaunchKernelGGL(k_prep, dim3(2080), dim3(256), 0, stream,
                     x, xb, Wqkv, wqkvt, Wout, woutt, Kp, Vp);
  hipLaunchKernelGGL(k_gemm1, dim3(24, 32), dim3(128), 0, stream,
                     xb, wqkvt, Qs, Kp, Vp);
  hipLaunchKernelGGL(k_attn, dim3(512), dim3(256), 0, stream, Qs, Kp, Vp, attnb);
  hipLaunchKernelGGL((k_gemm<64, 64>), dim3(8, 64), dim3(256), 0, stream,
                     attnb, woutt, (float*)d_out, bout, 4096, 512, 512);
}

// Round 11
// 36.632 us; speedup vs baseline: 1.0409x; 1.0409x over previous
//
#include <hip/hip_runtime.h>
#include <hip/hip_bf16.h>
#include <stdint.h>

typedef short short8 __attribute__((ext_vector_type(8)));
typedef float f32x4 __attribute__((ext_vector_type(4)));
typedef unsigned short ushort4_t __attribute__((ext_vector_type(4)));
typedef unsigned short ushort8_t __attribute__((ext_vector_type(8)));

#define S_LEN 2048
#define NQKV 1536
#define DMODEL 512

__device__ inline unsigned short f2bf(float f) {
  unsigned int u = __float_as_uint(f);
  unsigned int r = (u + 0x7FFFu + ((u >> 16) & 1u)) >> 16;
  return (unsigned short)r;
}

// async global->LDS, 16B per lane. LDS dest must be linear in lane order.
__device__ __forceinline__ void gll16(const unsigned short* g, unsigned short* l) {
  __builtin_amdgcn_global_load_lds(
      (const __attribute__((address_space(1))) unsigned int*)g,
      (__attribute__((address_space(3))) unsigned int*)l, 16, 0, 0);
}

// ---------------- fused prep: x->bf16, weight transposes, pad zeroing --------
__global__ __launch_bounds__(256) void k_prep(const float* __restrict__ x,
                                              unsigned short* __restrict__ xb,
                                              const float* __restrict__ w1,
                                              unsigned short* __restrict__ o1,
                                              const float* __restrict__ w2,
                                              unsigned short* __restrict__ o2,
                                              unsigned short* __restrict__ Kp,
                                              unsigned short* __restrict__ Vp) {
  __shared__ float T[32][33];
  int bid = blockIdx.x;
  int t = threadIdx.x;
  if (bid < 1024) {
    int i = (bid * 256 + t) * 8;
    float4 a = *(const float4*)(x + i);
    float4 b = *(const float4*)(x + i + 4);
    ushort8_t o;
    o[0] = f2bf(a.x); o[1] = f2bf(a.y); o[2] = f2bf(a.z); o[3] = f2bf(a.w);
    o[4] = f2bf(b.x); o[5] = f2bf(b.y); o[6] = f2bf(b.z); o[7] = f2bf(b.w);
    *(ushort8_t*)(xb + i) = o;
    return;
  }
  if (bid >= 2048) {  // pad zeroing: Kp rows [0,32)+[2080,2112); Vp cols same
    int p = bid - 2048;
    ushort8_t z = {};
    if (p < 16) {
      unsigned short* dst = Kp + (size_t)p * 2112 * 64;
#pragma unroll
      for (int i = 0; i < 2; i++) {
        int s = t + 256 * i;
        int row = s >> 3, c = s & 7;
        int r2 = row < 32 ? row : row - 32 + 2080;
        *(ushort8_t*)&dst[r2 * 64 + c * 8] = z;
      }
    } else {
      unsigned short* dst = Vp + (size_t)(p - 16) * 64 * 2112;
#pragma unroll
      for (int i = 0; i < 2; i++) {
        int s = t + 256 * i;
        int d = s >> 3, side = (s >> 2) & 1, c = s & 3;
        *(ushort8_t*)&dst[(size_t)d * 2112 + side * 2080 + c * 8] = z;
      }
    }
    return;
  }
  bid -= 1024;
  int bx = bid & 63, byy = bid >> 6;
  const float* w; unsigned short* o; int cols;
  if (bx < 48) { w = w1; o = o1; cols = 1536; }
  else         { w = w2; o = o2; cols = 512; bx -= 48; }
  int r0 = byy * 32, c0 = bx * 32;
  int tr = t / 32, tc = t % 32;
#pragma unroll
  for (int i = 0; i < 4; i++) {
    int r = tr + i * 8;
    T[r][tc] = w[(size_t)(r0 + r) * cols + c0 + tc];
  }
  __syncthreads();
#pragma unroll
  for (int i = 0; i < 4; i++) {
    int rr = tr + i * 8;
    o[(size_t)(c0 + rr) * 512 + r0 + tc] = f2bf(T[tc][rr]);
  }
}

// ---------------- GEMM: C[M][N] = A[M][K](bf16) * Bt[N][K](bf16)^T ----------------
// BMxBN tile, BK=64, 4 waves (2x2), global_load_lds staging (both-sides XOR
// swizzle: pre-swizzled global source chunk + same XOR on ds_read -> 2-way),
// 2-phase double buffer.
// MODE 0: f32 out + bias via LDS bounce, coalesced float4 stores.
// MODE 1 (BN=64): block's 64 cols are one pure q/k/v segment; swizzled bounce,
//                 contiguous 16B stores (Qs / Kp shifted / Vp transposed).
template <int BM, int BN, int MODE>
__global__ __launch_bounds__(256) void k_gemm(const unsigned short* __restrict__ A,
                                              const unsigned short* __restrict__ Bt,
                                              void* __restrict__ Cout,
                                              const float* __restrict__ bias,
                                              unsigned short* __restrict__ qs,
                                              unsigned short* __restrict__ kp,
                                              unsigned short* __restrict__ vp,
                                              int M, int N, int K) {
  constexpr int MR = BM / 32, NR = BN / 32;
  constexpr int CA = BM / 32, CB = BN / 32;        // 16B chunks/thread at BK=64
  constexpr int STAGE_SH = 2 * (BM + BN) * 64;
  constexpr int BOUNCE_SH = MODE == 0 ? BM * BN * 2 : BM * BN;
  constexpr int SMEM_SH = STAGE_SH > BOUNCE_SH ? STAGE_SH : BOUNCE_SH;
  __shared__ __align__(16) unsigned short smem[SMEM_SH];
  const int ASZ = BM * 64, BOFF = 2 * BM * 64, BSZ = BN * 64;

  const int t = threadIdx.x, lane = t & 63, wid = t >> 6;
  const int m0 = blockIdx.y * BM, n0 = blockIdx.x * BN;
  const int wm = (wid >> 1) * (BM / 2), wn = (wid & 1) * (BN / 2);
  const int lr = lane & 15, lg = lane >> 4;
  const unsigned short* Ab = A + (size_t)m0 * K;
  const unsigned short* Bb = Bt + (size_t)n0 * K;
  f32x4 acc[MR][NR] = {};

  const int NT = K / 64;
  auto stage = [&](int buf, int kt) {
#pragma unroll
    for (int c = 0; c < CA; c++) {
      int f = t + 256 * c;
      int row = f >> 3, ch = f & 7;
      gll16(Ab + (size_t)row * K + kt + ((ch ^ (row & 7)) << 3),
            &smem[buf * ASZ + f * 8]);
    }
#pragma unroll
    for (int c = 0; c < CB; c++) {
      int f = t + 256 * c;
      int row = f >> 3, ch = f & 7;
      gll16(Bb + (size_t)row * K + kt + ((ch ^ (row & 7)) << 3),
            &smem[BOFF + buf * BSZ + f * 8]);
    }
  };

  stage(0, 0);
  int buf = 0;
  for (int it = 0; it < NT; ++it) {
    __syncthreads();
    if (it + 1 < NT) stage(buf ^ 1, (it + 1) * 64);
    const unsigned short* Ap = &smem[buf * ASZ];
    const unsigned short* Bp = &smem[BOFF + buf * BSZ];
#pragma unroll
    for (int sl = 0; sl < 2; sl++) {
      const int cs = sl * 4 + lg;                  // 16B chunk within the row
      short8 af[MR], bfv[NR];
#pragma unroll
      for (int i = 0; i < MR; i++) {
        int row = wm + i * 16 + lr;
        af[i] = *(const short8*)&Ap[row * 64 + ((cs ^ (row & 7)) << 3)];
      }
#pragma unroll
      for (int i = 0; i < NR; i++) {
        int row = wn + i * 16 + lr;
        bfv[i] = *(const short8*)&Bp[row * 64 + ((cs ^ (row & 7)) << 3)];
      }
#pragma unroll
      for (int mi = 0; mi < MR; mi++)
#pragma unroll
        for (int ni = 0; ni < NR; ni++)
          acc[mi][ni] = __builtin_amdgcn_mfma_f32_16x16x32_bf16(af[mi], bfv[ni], acc[mi][ni], 0, 0, 0);
    }
    buf ^= 1;
  }

  if (MODE == 0) {
    // ---- f32 bounce: [BM][BN] f32, coalesced float4 stores + bias ----
    __syncthreads();
    float* ft = (float*)smem;
#pragma unroll
    for (int mi = 0; mi < MR; mi++)
#pragma unroll
      for (int ni = 0; ni < NR; ni++)
#pragma unroll
        for (int j = 0; j < 4; j++)
          ft[(wm + mi * 16 + lg * 4 + j) * BN + wn + ni * 16 + lr] = acc[mi][ni][j];
    __syncthreads();
#pragma unroll
    for (int i = 0; i < BM * BN / 1024; i++) {
      int s = t + 256 * i;
      int row = s / (BN / 4), ch = s % (BN / 4);
      float4 v = *(const float4*)&ft[row * BN + ch * 4];
      float4 bv = *(const float4*)&bias[n0 + ch * 4];
      v.x += bv.x; v.y += bv.y; v.z += bv.z; v.w += bv.w;
      *(float4*)&((float*)Cout)[(size_t)(m0 + row) * N + n0 + ch * 4] = v;
    }
  } else {
    // ---- swizzled bf16 bounce [BM][64]: u16 idx = row*64 + ((c ^ ((row>>3)&7))*8 + (col&7))
    __syncthreads();
#pragma unroll
    for (int mi = 0; mi < MR; mi++)
#pragma unroll
      for (int ni = 0; ni < NR; ni++)
#pragma unroll
        for (int j = 0; j < 4; j++) {
          int row = wm + mi * 16 + lg * 4 + j;
          int col = wn + ni * 16 + lr;
          smem[row * 64 + (((col >> 3) ^ ((row >> 3) & 7)) << 3) + (col & 7)] =
              f2bf(acc[mi][ni][j]);
        }
    __syncthreads();

    const int b_ = m0 >> 11;
    const int posb = m0 & 2047;
    const int h = n0 / 192, seg = (n0 % 192) >> 6;
    if (seg < 2) {
      unsigned short* dst = (seg == 0)
          ? qs + ((size_t)(b_ * 8 + h) * 2048 + posb) * 64
          : kp + ((size_t)(b_ * 8 + h) * 2112 + 32 + posb) * 64;
#pragma unroll
      for (int i = 0; i < BM / 32; i++) {
        int s = t + 256 * i;              // BM rows x 8 chunks
        int row = s >> 3, ch = s & 7;
        int src = row * 64 + ((ch ^ ((row >> 3) & 7)) << 3);
        *(ushort8_t*)&dst[s * 8] = *(const ushort8_t*)&smem[src];
      }
    } else {
      unsigned short* dst = vp + (size_t)(b_ * 8 + h) * 64 * 2112;
#pragma unroll
      for (int i = 0; i < BM / 32; i++) {
        int s = t + 256 * i;              // dl 0..63, pc 0..BM/8-1
        int dl = s / (BM / 8), pc = s % (BM / 8);
        ushort8_t v;
#pragma unroll
        for (int j = 0; j < 8; j++) {
          int row = pc * 8 + j;
          v[j] = smem[row * 64 + ((((dl >> 3) ^ (pc & 7)) << 3)) + (dl & 7)];
        }
        *(ushort8_t*)&dst[(size_t)dl * 2112 + 32 + posb + pc * 8] = v;
      }
    }
  }
}

// ---------------- windowed attention: 128-q blocks, 8 waves, LDS-staged ------
// Block = (b, h, 128 q). Staging duplication cut 26% vs 64-q blocks.
__global__ __launch_bounds__(512) void k_attn(const unsigned short* __restrict__ Qs,
                                              const unsigned short* __restrict__ Kp,
                                              const unsigned short* __restrict__ Vp,
                                              unsigned short* __restrict__ attnb) {
  __shared__ __align__(16) unsigned short Kt[192 * 64];  // pos-local x d, swz (24 KB)
  __shared__ __align__(16) unsigned short Vt[64 * 256];  // d x pos-local, swz (32 KB)
  __shared__ __align__(16) unsigned short Qt[128 * 64];  // q-local x d, swz  (16 KB)
  const int t = threadIdx.x, lane = t & 63, w = t >> 6;   // w 0..7
  const int blk = blockIdx.x;
  const int sbi = blk & 15, h = (blk >> 4) & 7, b = blk >> 7;
  const int sb = sbi * 128;
  const int bh = b * 8 + h;
  const int lr = lane & 15, lg = lane >> 4;

  {  // stage K: Kp idx sb..sb+191 (= global pos sb-32..sb+159)
    const unsigned short* src = Kp + ((size_t)bh * 2112 + sb) * 64;
#pragma unroll
    for (int i = 0; i < 3; i++) {
      int s = t + 512 * i, row = s >> 3, c = s & 7;
      gll16(src + row * 64 + (c ^ (row & 7)) * 8, &Kt[s * 8]);
    }
  }
  {  // stage V: Vp cols sb..sb+255 (= global pos sb-32..sb+223)
    const unsigned short* src = Vp + (size_t)bh * 64 * 2112 + sb;
#pragma unroll
    for (int i = 0; i < 4; i++) {
      int s = t + 512 * i, d = s >> 5, c = s & 31;
      gll16(src + (size_t)d * 2112 + (c ^ (d & 7)) * 8, &Vt[s * 8]);
    }
  }
  {  // stage Q: rows sb..sb+127
    const unsigned short* src = Qs + ((size_t)bh * 2048 + sb) * 64;
#pragma unroll
    for (int i = 0; i < 2; i++) {
      int s = t + 512 * i, row = s >> 3, c = s & 7;
      gll16(src + row * 64 + (c ^ (row & 7)) * 8, &Qt[s * 8]);
    }
  }
  __syncthreads();

  const int sw = (lr & 7) << 3;  // u16 read-XOR (16B chunks); rows are 16-aligned
                                 // per wave so row&7 == lr&7 everywhere below.

  short8 qb[2];
#pragma unroll
  for (int ks = 0; ks < 2; ks++)
    qb[ks] = *(const short8*)&Qt[(w * 16 + lr) * 64 + ((ks * 32 + lg * 8) ^ sw)];

  // S^T: col = q = lr, row = pos_local(rel s0-32) = ct*16 + lg*4 + j
  f32x4 sc[5] = {};
#pragma unroll
  for (int ct = 0; ct < 5; ct++) {
#pragma unroll
    for (int ks = 0; ks < 2; ks++) {
      short8 ka = *(const short8*)&Kt[(w * 16 + ct * 16 + lr) * 64 + ((ks * 32 + lg * 8) ^ sw)];
      sc[ct] = __builtin_amdgcn_mfma_f32_16x16x32_bf16(ka, qb[ks], sc[ct], 0, 0, 0);
    }
  }

  float mx = -1e30f;
#pragma unroll
  for (int ct = 0; ct < 5; ct++)
#pragma unroll
    for (int j = 0; j < 4; j++) {
      int c2 = ct * 16 + lg * 4 + j;
      sc[ct][j] = (c2 >= lr && c2 <= lr + 64) ? sc[ct][j] * 0.125f : -1e30f;
      mx = fmaxf(mx, sc[ct][j]);
    }
  mx = fmaxf(mx, __shfl_xor(mx, 16, 64));
  mx = fmaxf(mx, __shfl_xor(mx, 32, 64));

  float pn[5][4];
  float sum = 0.0f;
#pragma unroll
  for (int ct = 0; ct < 5; ct++)
#pragma unroll
    for (int j = 0; j < 4; j++) {
      pn[ct][j] = __expf(sc[ct][j] - mx);
      sum += pn[ct][j];
    }
  sum += __shfl_xor(sum, 16, 64);
  sum += __shfl_xor(sum, 32, 64);
  float inv = 1.0f / sum;

  unsigned int w01[5], w23[5];
#pragma unroll
  for (int ct = 0; ct < 5; ct++) {
    w01[ct] = (unsigned int)f2bf(pn[ct][0] * inv) | ((unsigned int)f2bf(pn[ct][1] * inv) << 16);
    w23[ct] = (unsigned int)f2bf(pn[ct][2] * inv) | ((unsigned int)f2bf(pn[ct][3] * inv) << 16);
  }

  f32x4 oa[4] = {};
  const int h2 = lg & 1, tl = lg >> 1;
  const int sA = 32 * h2 + lr, sB = sA + 16;
#pragma unroll
  for (int ks = 0; ks < 3; ks++) {
    const int T0 = 2 * ks;
    const int T1 = (2 * ks + 1 < 5) ? (2 * ks + 1) : 4;
    unsigned int a0 = __shfl((int)w01[T0], sA, 64), a1 = __shfl((int)w23[T0], sA, 64);
    unsigned int a2 = __shfl((int)w01[T0], sB, 64), a3 = __shfl((int)w23[T0], sB, 64);
    unsigned int b0 = __shfl((int)w01[T1], sA, 64), b1 = __shfl((int)w23[T1], sA, 64);
    unsigned int b2 = __shfl((int)w01[T1], sB, 64), b3 = __shfl((int)w23[T1], sB, 64);
    union { unsigned int u[4]; short8 v; } pb;
    pb.u[0] = tl ? b0 : a0;
    pb.u[1] = tl ? b1 : a1;
    pb.u[2] = tl ? b2 : a2;
    pb.u[3] = tl ? b3 : a3;
    if (ks == 2 && tl) { pb.u[0] = 0; pb.u[1] = 0; pb.u[2] = 0; pb.u[3] = 0; }
    int pofl = w * 16 + ks * 32 + lg * 8;
#pragma unroll
    for (int nt = 0; nt < 4; nt++) {
      short8 va = *(const short8*)&Vt[(nt * 16 + lr) * 256 + (pofl ^ sw)];
      oa[nt] = __builtin_amdgcn_mfma_f32_16x16x32_bf16(va, pb.v, oa[nt], 0, 0, 0);
    }
  }

  const int s0 = sb + w * 16;
#pragma unroll
  for (int nt = 0; nt < 4; nt++) {
    ushort4_t o;
#pragma unroll
    for (int j = 0; j < 4; j++) o[j] = f2bf(oa[nt][j]);
    *(ushort4_t*)&attnb[((size_t)b * S_LEN + s0 + lr) * DMODEL + h * 64 + nt * 16 + lg * 4] = o;
  }
}

// ---------------- launch ----------------
extern "C" void kernel_launch(void* const* d_in, const int* in_sizes, int n_in,
                              void* d_out, int out_size, void* d_ws, size_t ws_size,
                              hipStream_t stream) {
  const float* x    = (const float*)d_in[0];
  const float* Wqkv = (const float*)d_in[1];
  const float* Wout = (const float*)d_in[2];
  const float* bout = (const float*)d_in[3];
  char* ws = (char*)d_ws;
  unsigned short* xb    = (unsigned short*)(ws + 0);         // 4096x512 bf16 (4 MB)
  unsigned short* wqkvt = (unsigned short*)(ws + 4194304);   // 1536x512 bf16 (1.5 MB)
  unsigned short* woutt = (unsigned short*)(ws + 5767168);   // 512x512 bf16  (0.5 MB)
  unsigned short* Qs    = (unsigned short*)(ws + 6291456);   // [16][2048][64] (4 MB)
  unsigned short* Kp    = (unsigned short*)(ws + 10485760);  // [16][2112][64] (4.125 MB)
  unsigned short* Vp    = (unsigned short*)(ws + 14811136);  // [16][64][2112] (4.125 MB + slack)
  unsigned short* attnb = (unsigned short*)(ws + 19922944);  // 4096x512 bf16 (4 MB)

  hipLaunchKernelGGL(k_prep, dim3(2080), dim3(256), 0, stream,
                     x, xb, Wqkv, wqkvt, Wout, woutt, Kp, Vp);
  hipLaunchKernelGGL((k_gemm<128, 64, 1>), dim3(24, 32), dim3(256), 0, stream,
                     xb, wqkvt, nullptr, (const float*)nullptr, Qs, Kp, Vp, 4096, 1536, 512);
  hipLaunchKernelGGL(k_attn, dim3(256), dim3(512), 0, stream, Qs, Kp, Vp, attnb);
  hipLaunchKernelGGL((k_gemm<64, 64, 0>), dim3(8, 64), dim3(256), 0, stream,
                     attnb, woutt, d_out, bout,
                     (unsigned short*)nullptr, (unsigned short*)nullptr,
                     (unsigned short*)nullptr, 4096, 512, 512);
}